// Round 1
// baseline (839.161 us; speedup 1.0000x reference)
//
#include <hip/hip_runtime.h>
#include <stdint.h>

#define PTOT 2784
#define PM1  2783
#define DDIM 1408
#define NB   8
#define ROWS 22272        // NB*PTOT
#define KHEAD 2816        // 2*DDIM
#define ATTW_PAD 2816     // padded rows of att_w (multiple of 128)

typedef __attribute__((ext_vector_type(8))) short bf16x8;
typedef __attribute__((ext_vector_type(4))) float f32x4;
typedef __attribute__((ext_vector_type(4))) int   i32x4;

__device__ __forceinline__ short f2bf_rne(float x) {
    uint32_t u = __float_as_uint(x);
    u += 0x7fffu + ((u >> 16) & 1u);
    return (short)(u >> 16);
}
__device__ __forceinline__ short f2bf_trunc(float x) {
    return (short)(__float_as_uint(x) >> 16);
}

// async global->LDS, 16B per lane. lds dest = wave-uniform base + lane*16.
__device__ __forceinline__ void gld16(const void* g, void* l) {
    __builtin_amdgcn_global_load_lds(
        (const __attribute__((address_space(1))) void*)(uintptr_t)g,
        (__attribute__((address_space(3))) void*)(uint32_t)(uintptr_t)l,
        16, 0, 0);
}

// ---------------- kernel 1: 1x1 conv -> feat (f32, written to d_out) ----------
__global__ __launch_bounds__(256) void k_conv(
    const float* __restrict__ x, const float* __restrict__ w,
    const float* __restrict__ cb, float* __restrict__ feat) {
  __shared__ float xs[256 * 32];
  int b = blockIdx.x / 28;
  int t0 = (blockIdx.x % 28) * 32;
  int t = threadIdx.x;
  for (int i = t; i < 256 * 32; i += 256) {
    int c = i >> 5, pos = i & 31;
    int hw = t0 + pos;
    xs[i] = (hw < 880) ? x[((size_t)b * 256 + c) * 880 + hw] : 0.f;
  }
  __syncthreads();
  int o = t & 63, g = t >> 6;
  float acc[8];
#pragma unroll
  for (int pp = 0; pp < 8; ++pp) acc[pp] = cb[o];
  const float* wr = w + o * 256;
  for (int c = 0; c < 256; ++c) {
    float wv = wr[c];
#pragma unroll
    for (int pp = 0; pp < 8; ++pp) acc[pp] += wv * xs[c * 32 + g + pp * 4];
  }
#pragma unroll
  for (int pp = 0; pp < 8; ++pp) {
    int hw = t0 + g + pp * 4;
    if (hw < 880) feat[((size_t)b * 64 + o) * 880 + hw] = acc[pp];
  }
}

// ---------------- kernel 2: prep (bf16 weights, bias, M diag) -----------------
__global__ __launch_bounds__(256) void k_prep(
    const float* __restrict__ att_w, const float* __restrict__ cls_w,
    const float* __restrict__ so_w, const float* __restrict__ reg_w,
    const float* __restrict__ cls_b, const float* __restrict__ so_b,
    const float* __restrict__ reg_b,
    short* __restrict__ attw, short* __restrict__ wbf,
    float* __restrict__ bias80, float* __restrict__ M) {
  const int64_t n_attw = (int64_t)ATTW_PAD * DDIM;
  const int64_t n_w = 80 * (int64_t)KHEAD;
  const int64_t total = n_attw + n_w + 80 + ROWS;
  for (int64_t i = (int64_t)blockIdx.x * 256 + threadIdx.x; i < total;
       i += (int64_t)gridDim.x * 256) {
    if (i < n_attw) {
      int j = (int)(i / DDIM), k = (int)(i - (int64_t)j * DDIM);
      float v = (j < PM1) ? att_w[(size_t)j * DDIM + k] : 0.f;
      attw[i] = f2bf_rne(v);
    } else if (i < n_attw + n_w) {
      int64_t ii = i - n_attw;
      int n = (int)(ii / KHEAD), k = (int)(ii - (int64_t)n * KHEAD);
      float v = 0.f;
      if (n < 2) v = cls_w[n * KHEAD + k];
      else if (n == 2) v = so_w[k];
      else if (n < 76) v = reg_w[(size_t)(n - 3) * KHEAD + k];
      wbf[ii] = f2bf_rne(v);
    } else if (i < n_attw + n_w + 80) {
      int n = (int)(i - n_attw - n_w);
      float v = 0.f;
      if (n < 2) v = cls_b[n];
      else if (n == 2) v = so_b[0];
      else if (n < 76) v = reg_b[n - 3];
      bias80[n] = v;
    } else {
      int r = (int)(i - n_attw - n_w - 80);
      int p = r % PTOT;
      M[(size_t)r * PTOT + p] = -1e30f;   // softmax -> exact 0 on diagonal
    }
  }
}

// ---------------- kernel 3: gather rois -> baf (bf16) and bafT (bf16) ---------
__global__ __launch_bounds__(256) void k_gather(
    const float* __restrict__ feat, const int* __restrict__ cutx,
    const unsigned char* __restrict__ inval,
    short* __restrict__ baf, short* __restrict__ bafT) {
  int p0 = blockIdx.x * 64, d0 = blockIdx.y * 64, b = blockIdx.z;
  __shared__ short tile[64][72];
  int t = threadIdx.x;
  for (int i = t; i < 64 * 64; i += 256) {
    int pl = i >> 6, dl = i & 63;
    int p = p0 + pl, d = d0 + dl;
    float v = 0.f;
    if (p < PTOT) {
      int c = d / 22, h = d - c * 22;
      if (!inval[p * 22 + h]) {
        int xc = cutx[p * 22 + h];
        v = feat[(((size_t)b * 64 + c) * 22 + h) * 40 + xc];
      }
    }
    tile[pl][dl] = f2bf_rne(v);
  }
  __syncthreads();
  for (int u = t; u < 512; u += 256) {   // baf rows: coalesced along d
    int pl = u >> 3, dg = u & 7;
    int p = p0 + pl;
    if (p < PTOT) {
      bf16x8 v;
#pragma unroll
      for (int e = 0; e < 8; ++e) v[e] = tile[pl][dg * 8 + e];
      *(bf16x8*)&baf[((size_t)b * PTOT + p) * DDIM + d0 + dg * 8] = v;
    }
  }
  for (int u = t; u < 512; u += 256) {   // bafT rows: coalesced along p
    int dl = u >> 3, pg = u & 7;
    if (p0 + pg * 8 + 7 < PTOT) {
      bf16x8 v;
#pragma unroll
      for (int e = 0; e < 8; ++e) v[e] = tile[pg * 8 + e][dl];
      *(bf16x8*)&bafT[((size_t)b * DDIM + d0 + dl) * PTOT + p0 + pg * 8] = v;
    }
  }
}

// ---------------- kernel 4: scores GEMM -> scatter into M (with diag shift) ---
__global__ __launch_bounds__(256) void k_scores(
    const short* __restrict__ baf, const short* __restrict__ attw,
    const float* __restrict__ att_b, float* __restrict__ M) {
  __shared__ short smA[128 * 32];
  __shared__ short smB[128 * 32];
  const int nwg = 174 * 22;
  int wg = blockIdx.x;
  int qn = nwg >> 3, rn = nwg & 7;
  int xcd = wg & 7, lin = wg >> 3;
  int wgid = (xcd < rn) ? (xcd * (qn + 1) + lin)
                        : (rn * (qn + 1) + (xcd - rn) * qn + lin);
  int it = wgid / 22, nt = wgid - it * 22;   // n fastest -> A-panel L2 reuse
  int m0 = it * 128, n0 = nt * 128;
  int t = threadIdx.x, wid = t >> 6, lane = t & 63;
  int rowa = t >> 2, kga = t & 3;
  const short* a0 = baf + (size_t)(m0 + rowa) * DDIM + kga * 8;
  const short* a1 = a0 + (size_t)64 * DDIM;
  const short* b0 = attw + (size_t)(n0 + rowa) * DDIM + kga * 8;
  const short* b1 = b0 + (size_t)64 * DDIM;
  char* lA0 = (char*)smA + wid * 1024; char* lA1 = lA0 + 4096;
  char* lB0 = (char*)smB + wid * 1024; char* lB1 = lB0 + 4096;
  int wr = wid >> 1, wc = wid & 1, lr = lane & 15, lg = lane >> 4;
  const short* pA = smA + (wr * 64 + lr) * 32 + lg * 8;
  const short* pB = smB + (wc * 64 + lr) * 32 + lg * 8;
  f32x4 acc[4][4];
  const f32x4 fz = {0.f, 0.f, 0.f, 0.f};
  for (int i2 = 0; i2 < 4; ++i2) for (int j2 = 0; j2 < 4; ++j2) acc[i2][j2] = fz;
  for (int k0 = 0; k0 < DDIM; k0 += 32) {
    gld16(a0, lA0); gld16(a1, lA1); gld16(b0, lB0); gld16(b1, lB1);
    a0 += 32; a1 += 32; b0 += 32; b1 += 32;
    __syncthreads();
    bf16x8 af[4], bv[4];
#pragma unroll
    for (int mi = 0; mi < 4; ++mi) af[mi] = *(const bf16x8*)(pA + mi * 512);
#pragma unroll
    for (int ni = 0; ni < 4; ++ni) bv[ni] = *(const bf16x8*)(pB + ni * 512);
#pragma unroll
    for (int mi = 0; mi < 4; ++mi)
#pragma unroll
      for (int ni = 0; ni < 4; ++ni)
        acc[mi][ni] = __builtin_amdgcn_mfma_f32_16x16x32_bf16(af[mi], bv[ni], acc[mi][ni], 0, 0, 0);
    __syncthreads();
  }
#pragma unroll
  for (int mi = 0; mi < 4; ++mi) {
#pragma unroll
    for (int rg = 0; rg < 4; ++rg) {
      int gm = m0 + wr * 64 + mi * 16 + lg * 4 + rg;
      int bb = gm / PTOT;
      int i = gm - bb * PTOT;
      float* Mrow = M + (size_t)gm * PTOT;
#pragma unroll
      for (int ni = 0; ni < 4; ++ni) {
        int j = n0 + wc * 64 + ni * 16 + lr;
        if (j < PM1) {
          int q2 = j + (j >= i);
          Mrow[q2] = acc[mi][ni][rg] + att_b[j];
        }
      }
    }
  }
}

// ---------------- kernel 5: row softmax in place on M -------------------------
__global__ __launch_bounds__(256) void k_softmax(float* __restrict__ M) {
  __shared__ float red[8];
  float* pr = M + (size_t)blockIdx.x * PTOT;
  int t = threadIdx.x;
  float v[11];
  float mx = -3.0e38f;
#pragma unroll
  for (int j = 0; j < 11; ++j) {
    int q = t + j * 256;
    v[j] = (q < PTOT) ? pr[q] : -3.0e38f;
    mx = fmaxf(mx, v[j]);
  }
#pragma unroll
  for (int off = 32; off; off >>= 1) mx = fmaxf(mx, __shfl_xor(mx, off));
  if ((t & 63) == 0) red[t >> 6] = mx;
  __syncthreads();
  mx = fmaxf(fmaxf(red[0], red[1]), fmaxf(red[2], red[3]));
  float s = 0.f;
#pragma unroll
  for (int j = 0; j < 11; ++j) { v[j] = __expf(v[j] - mx); s += v[j]; }
#pragma unroll
  for (int off = 32; off; off >>= 1) s += __shfl_xor(s, off);
  if ((t & 63) == 0) red[4 + (t >> 6)] = s;
  __syncthreads();
  s = (red[4] + red[5]) + (red[6] + red[7]);
  float inv = 1.f / s;
#pragma unroll
  for (int j = 0; j < 11; ++j) {
    int q = t + j * 256;
    if (q < PTOT) pr[q] = v[j] * inv;
  }
}

// ---------------- kernel 6: att_feats = M @ baf  (per batch) ------------------
__global__ __launch_bounds__(256) void k_attfeat(
    const float* __restrict__ M, const short* __restrict__ bafT,
    short* __restrict__ attf) {
  __shared__ short smA[128 * 32];
  __shared__ short smB[128 * 32];
  int wg = blockIdx.x;                       // 1936 = 8*22*11, divisible by 8
  int xcd = wg & 7, lin = wg >> 3;
  int wgid = xcd * 242 + lin;
  int bb = wgid / 242; int rem = wgid - bb * 242;
  int it = rem / 11, dt = rem - it * 11;     // d fastest -> A-panel L2 reuse
  int i0 = it * 128, d0 = dt * 128;
  int t = threadIdx.x, wid = t >> 6, lane = t & 63;
  int rowa = t >> 2, kga = t & 3;
  const float* sA0 = M + ((size_t)(bb * PTOT + i0 + rowa)) * PTOT + kga * 8;
  const float* sA1 = sA0 + (size_t)64 * PTOT;
  short* dA0 = smA + rowa * 32 + kga * 8;
  short* dA1 = dA0 + 64 * 32;
  const short* sB0 = bafT + ((size_t)(bb * DDIM + d0 + rowa)) * PTOT + kga * 8;
  const short* sB1 = sB0 + (size_t)64 * PTOT;
  char* lB0 = (char*)smB + wid * 1024; char* lB1 = lB0 + 4096;
  int wr = wid >> 1, wc = wid & 1, lr = lane & 15, lg = lane >> 4;
  const short* pA = smA + (wr * 64 + lr) * 32 + lg * 8;
  const short* pB = smB + (wc * 64 + lr) * 32 + lg * 8;
  f32x4 acc[4][4];
  const f32x4 fz = {0.f, 0.f, 0.f, 0.f};
  for (int i2 = 0; i2 < 4; ++i2) for (int j2 = 0; j2 < 4; ++j2) acc[i2][j2] = fz;
  for (int k0 = 0; k0 < PTOT; k0 += 32) {
    gld16(sB0, lB0); gld16(sB1, lB1);
    f32x4 u0 = *(const f32x4*)sA0;
    f32x4 u1 = *(const f32x4*)(sA0 + 4);
    f32x4 u2 = *(const f32x4*)sA1;
    f32x4 u3 = *(const f32x4*)(sA1 + 4);
    bf16x8 v0, v1;
#pragma unroll
    for (int e = 0; e < 4; ++e) {
      v0[e] = f2bf_trunc(u0[e]); v0[4 + e] = f2bf_trunc(u1[e]);
      v1[e] = f2bf_trunc(u2[e]); v1[4 + e] = f2bf_trunc(u3[e]);
    }
    *(bf16x8*)dA0 = v0;
    *(bf16x8*)dA1 = v1;
    sA0 += 32; sA1 += 32; sB0 += 32; sB1 += 32;
    __syncthreads();
    bf16x8 af[4], bv[4];
#pragma unroll
    for (int mi = 0; mi < 4; ++mi) af[mi] = *(const bf16x8*)(pA + mi * 512);
#pragma unroll
    for (int ni = 0; ni < 4; ++ni) bv[ni] = *(const bf16x8*)(pB + ni * 512);
#pragma unroll
    for (int mi = 0; mi < 4; ++mi)
#pragma unroll
      for (int ni = 0; ni < 4; ++ni)
        acc[mi][ni] = __builtin_amdgcn_mfma_f32_16x16x32_bf16(af[mi], bv[ni], acc[mi][ni], 0, 0, 0);
    __syncthreads();
  }
#pragma unroll
  for (int mi = 0; mi < 4; ++mi) {
#pragma unroll
    for (int rg = 0; rg < 4; ++rg) {
      int i = i0 + wr * 64 + mi * 16 + lg * 4 + rg;
      if (i < PTOT) {
        short* arow = attf + ((size_t)(bb * PTOT + i)) * DDIM + d0 + wc * 64;
#pragma unroll
        for (int ni = 0; ni < 4; ++ni) arow[ni * 16 + lr] = f2bf_rne(acc[mi][ni][rg]);
      }
    }
  }
}

// ---------------- kernel 7: heads GEMM + proposal assembly --------------------
__global__ __launch_bounds__(256) void k_head(
    const short* __restrict__ attf, const short* __restrict__ baf,
    const short* __restrict__ wbf, const float* __restrict__ bias80,
    const float* __restrict__ anch, float* __restrict__ out) {
  __shared__ short smA[64 * 32];
  __shared__ short smB[80 * 32];
  int r0 = blockIdx.x * 64;
  int t = threadIdx.x, wid = t >> 6, lane = t & 63;
  int rowa = t >> 2, kg = t & 3;
  const short* sA_att = attf + (size_t)(r0 + rowa) * DDIM + kg * 8;
  const short* sA_baf = baf + (size_t)(r0 + rowa) * DDIM + kg * 8;
  const short* sB0 = wbf + (size_t)rowa * KHEAD + kg * 8;
  const short* sB1 = wbf + (size_t)(64 + (t >> 2)) * KHEAD + (t & 3) * 8;
  char* lA = (char*)smA + wid * 1024;
  char* lB0 = (char*)smB + wid * 1024;
  char* lB1 = (char*)smB + 4096;
  int lr = lane & 15, lg = lane >> 4;
  const short* pA = smA + (wid * 16 + lr) * 32 + lg * 8;
  const short* pB = smB + lr * 32 + lg * 8;
  f32x4 acc[5];
  const f32x4 fz = {0.f, 0.f, 0.f, 0.f};
  for (int i2 = 0; i2 < 5; ++i2) acc[i2] = fz;
  for (int ks = 0; ks < 88; ++ks) {
    const short* sA = (ks < 44) ? (sA_att + ks * 32) : (sA_baf + (ks - 44) * 32);
    gld16(sA, lA);
    gld16(sB0 + ks * 32, lB0);
    if (t < 64) gld16(sB1 + ks * 32, lB1);
    __syncthreads();
    bf16x8 a = *(const bf16x8*)pA;
#pragma unroll
    for (int ni = 0; ni < 5; ++ni) {
      bf16x8 b = *(const bf16x8*)(pB + ni * 512);
      acc[ni] = __builtin_amdgcn_mfma_f32_16x16x32_bf16(a, b, acc[ni], 0, 0, 0);
    }
    __syncthreads();
  }
#pragma unroll
  for (int ni = 0; ni < 5; ++ni) {
#pragma unroll
    for (int rg = 0; rg < 4; ++rg) {
      int n = ni * 16 + lr;
      int i = wid * 16 + lg * 4 + rg;
      int rgl = r0 + i;
      int p = rgl % PTOT;
      float v = acc[ni][rg] + bias80[n];
      if (n < 2) {
        out[(size_t)rgl * 77 + n] = v;
      } else if (n == 2) {
        out[(size_t)rgl * 77 + 2] =
            (anch[(size_t)p * 77 + 2] + 1.f / (1.f + __expf(-v))) * 0.5f;
        out[(size_t)rgl * 77 + 3] = anch[(size_t)p * 77 + 3];
      } else if (n < 76) {
        out[(size_t)rgl * 77 + n + 1] = v + anch[(size_t)p * 77 + n + 1];
      }
    }
  }
}

extern "C" void kernel_launch(void* const* d_in, const int* in_sizes, int n_in,
                              void* d_out, int out_size, void* d_ws, size_t ws_size,
                              hipStream_t stream) {
  const float* x      = (const float*)d_in[0];
  const float* conv_w = (const float*)d_in[1];
  const float* conv_b = (const float*)d_in[2];
  const float* att_w  = (const float*)d_in[3];
  const float* att_b  = (const float*)d_in[4];
  const float* cls_w  = (const float*)d_in[5];
  const float* cls_b  = (const float*)d_in[6];
  const float* so_w   = (const float*)d_in[7];
  const float* so_b   = (const float*)d_in[8];
  const float* reg_w  = (const float*)d_in[9];
  const float* reg_b  = (const float*)d_in[10];
  const float* anchors= (const float*)d_in[11];
  const int*   cut_xs = (const int*)d_in[12];
  const unsigned char* invalid = (const unsigned char*)d_in[13];

  float* out_rp = (float*)d_out;
  float* Mmat = out_rp + (size_t)ROWS * 77;              // 1,714,944
  float* feat = Mmat + (size_t)ROWS * PTOT;              // + 62,005,248

  char* wsp = (char*)d_ws;
  short* baf    = (short*)wsp;                           // 62,717,952 B
  short* bafT   = (short*)(wsp + 62717952ULL);           // 62,717,952 B
  short* attw   = (short*)(wsp + 125435904ULL);          //  7,929,856 B
  short* wbf    = (short*)(wsp + 133365760ULL);          //    450,560 B
  float* bias80 = (float*)(wsp + 133816320ULL);          //        512 B
  short* attf   = (short*)(wsp + 133816832ULL);          // 62,717,952 B -> 196.5 MB total

  k_conv<<<224, 256, 0, stream>>>(x, conv_w, conv_b, feat);
  k_prep<<<2048, 256, 0, stream>>>(att_w, cls_w, so_w, reg_w, cls_b, so_b, reg_b,
                                   attw, wbf, bias80, Mmat);
  k_gather<<<dim3(44, 22, 8), 256, 0, stream>>>(feat, cut_xs, invalid, baf, bafT);
  k_scores<<<174 * 22, 256, 0, stream>>>(baf, attw, att_b, Mmat);
  k_softmax<<<ROWS, 256, 0, stream>>>(Mmat);
  k_attfeat<<<1936, 256, 0, stream>>>(Mmat, bafT, attf);
  k_head<<<348, 256, 0, stream>>>(attf, baf, wbf, bias80, anchors, out_rp);
}

// Round 2
// 837.765 us; speedup vs baseline: 1.0017x; 1.0017x over previous
//
#include <hip/hip_runtime.h>
#include <stdint.h>

#define PTOT 2784
#define PM1  2783
#define DDIM 1408
#define NB   8
#define ROWS 22272        // NB*PTOT
#define KHEAD 2816        // 2*DDIM
#define ATTW_PAD 2816     // padded rows of att_w (multiple of 128)

typedef __attribute__((ext_vector_type(8))) short bf16x8;
typedef __attribute__((ext_vector_type(4))) float f32x4;

__device__ __forceinline__ short f2bf_rne(float x) {
    uint32_t u = __float_as_uint(x);
    u += 0x7fffu + ((u >> 16) & 1u);
    return (short)(u >> 16);
}
__device__ __forceinline__ short f2bf_trunc(float x) {
    return (short)(__float_as_uint(x) >> 16);
}

// async global->LDS, 16B per lane. lds dest = wave-uniform base + lane*16.
__device__ __forceinline__ void gld16(const void* g, void* l) {
    __builtin_amdgcn_global_load_lds(
        (const __attribute__((address_space(1))) void*)(uintptr_t)g,
        (__attribute__((address_space(3))) void*)(uint32_t)(uintptr_t)l,
        16, 0, 0);
}

// ---------------- kernel 1: 1x1 conv -> feat (f32, written to d_out) ----------
__global__ __launch_bounds__(256) void k_conv(
    const float* __restrict__ x, const float* __restrict__ w,
    const float* __restrict__ cb, float* __restrict__ feat) {
  __shared__ float xs[256 * 32];
  int b = blockIdx.x / 28;
  int t0 = (blockIdx.x % 28) * 32;
  int t = threadIdx.x;
  for (int i = t; i < 256 * 32; i += 256) {
    int c = i >> 5, pos = i & 31;
    int hw = t0 + pos;
    xs[i] = (hw < 880) ? x[((size_t)b * 256 + c) * 880 + hw] : 0.f;
  }
  __syncthreads();
  int o = t & 63, g = t >> 6;
  float acc[8];
#pragma unroll
  for (int pp = 0; pp < 8; ++pp) acc[pp] = cb[o];
  const float* wr = w + o * 256;
  for (int c = 0; c < 256; ++c) {
    float wv = wr[c];
#pragma unroll
    for (int pp = 0; pp < 8; ++pp) acc[pp] += wv * xs[c * 32 + g + pp * 4];
  }
#pragma unroll
  for (int pp = 0; pp < 8; ++pp) {
    int hw = t0 + g + pp * 4;
    if (hw < 880) feat[((size_t)b * 64 + o) * 880 + hw] = acc[pp];
  }
}

// ---------------- kernel 2: prep (bf16 weights, bias, M diag) -----------------
__global__ __launch_bounds__(256) void k_prep(
    const float* __restrict__ att_w, const float* __restrict__ cls_w,
    const float* __restrict__ so_w, const float* __restrict__ reg_w,
    const float* __restrict__ cls_b, const float* __restrict__ so_b,
    const float* __restrict__ reg_b,
    short* __restrict__ attw, short* __restrict__ wbf,
    float* __restrict__ bias80, float* __restrict__ M) {
  const int64_t n_attw = (int64_t)ATTW_PAD * DDIM;
  const int64_t n_w = 80 * (int64_t)KHEAD;
  const int64_t total = n_attw + n_w + 80 + ROWS;
  for (int64_t i = (int64_t)blockIdx.x * 256 + threadIdx.x; i < total;
       i += (int64_t)gridDim.x * 256) {
    if (i < n_attw) {
      int j = (int)(i / DDIM), k = (int)(i - (int64_t)j * DDIM);
      float v = (j < PM1) ? att_w[(size_t)j * DDIM + k] : 0.f;
      attw[i] = f2bf_rne(v);
    } else if (i < n_attw + n_w) {
      int64_t ii = i - n_attw;
      int n = (int)(ii / KHEAD), k = (int)(ii - (int64_t)n * KHEAD);
      float v = 0.f;
      if (n < 2) v = cls_w[n * KHEAD + k];
      else if (n == 2) v = so_w[k];
      else if (n < 76) v = reg_w[(size_t)(n - 3) * KHEAD + k];
      wbf[ii] = f2bf_rne(v);
    } else if (i < n_attw + n_w + 80) {
      int n = (int)(i - n_attw - n_w);
      float v = 0.f;
      if (n < 2) v = cls_b[n];
      else if (n == 2) v = so_b[0];
      else if (n < 76) v = reg_b[n - 3];
      bias80[n] = v;
    } else {
      int r = (int)(i - n_attw - n_w - 80);
      int p = r % PTOT;
      M[(size_t)r * PTOT + p] = -1e30f;   // softmax -> exact 0 on diagonal
    }
  }
}

// ---------------- kernel 3: gather rois -> baf (bf16) and bafT (bf16) ---------
__global__ __launch_bounds__(256) void k_gather(
    const float* __restrict__ feat, const int* __restrict__ cutx,
    const unsigned char* __restrict__ inval,
    short* __restrict__ baf, short* __restrict__ bafT) {
  int p0 = blockIdx.x * 64, d0 = blockIdx.y * 64, b = blockIdx.z;
  __shared__ short tile[64][72];
  int t = threadIdx.x;
  for (int i = t; i < 64 * 64; i += 256) {
    int pl = i >> 6, dl = i & 63;
    int p = p0 + pl, d = d0 + dl;
    float v = 0.f;
    if (p < PTOT) {
      int c = d / 22, h = d - c * 22;
      if (!inval[p * 22 + h]) {
        int xc = cutx[p * 22 + h];
        v = feat[(((size_t)b * 64 + c) * 22 + h) * 40 + xc];
      }
    }
    tile[pl][dl] = f2bf_rne(v);
  }
  __syncthreads();
  for (int u = t; u < 512; u += 256) {   // baf rows: coalesced along d
    int pl = u >> 3, dg = u & 7;
    int p = p0 + pl;
    if (p < PTOT) {
      bf16x8 v;
#pragma unroll
      for (int e = 0; e < 8; ++e) v[e] = tile[pl][dg * 8 + e];
      *(bf16x8*)&baf[((size_t)b * PTOT + p) * DDIM + d0 + dg * 8] = v;
    }
  }
  for (int u = t; u < 512; u += 256) {   // bafT rows: coalesced along p
    int dl = u >> 3, pg = u & 7;
    if (p0 + pg * 8 + 7 < PTOT) {
      bf16x8 v;
#pragma unroll
      for (int e = 0; e < 8; ++e) v[e] = tile[pg * 8 + e][dl];
      *(bf16x8*)&bafT[((size_t)b * DDIM + d0 + dl) * PTOT + p0 + pg * 8] = v;
    }
  }
}

// ---------------- kernel 4: scores GEMM -> scatter into M (with diag shift) ---
__global__ __launch_bounds__(256) void k_scores(
    const short* __restrict__ baf, const short* __restrict__ attw,
    const float* __restrict__ att_b, float* __restrict__ M) {
  __shared__ short smA[128 * 32];
  __shared__ short smB[128 * 32];
  const int nwg = 174 * 22;
  int wg = blockIdx.x;
  int qn = nwg >> 3, rn = nwg & 7;
  int xcd = wg & 7, lin = wg >> 3;
  int wgid = (xcd < rn) ? (xcd * (qn + 1) + lin)
                        : (rn * (qn + 1) + (xcd - rn) * qn + lin);
  int it = wgid / 22, nt = wgid - it * 22;   // n fastest -> A-panel L2 reuse
  int m0 = it * 128, n0 = nt * 128;
  int t = threadIdx.x, wid = t >> 6, lane = t & 63;
  int rowa = t >> 2, kga = t & 3;
  const short* a0 = baf + (size_t)(m0 + rowa) * DDIM + kga * 8;
  const short* a1 = a0 + (size_t)64 * DDIM;
  const short* b0 = attw + (size_t)(n0 + rowa) * DDIM + kga * 8;
  const short* b1 = b0 + (size_t)64 * DDIM;
  char* lA0 = (char*)smA + wid * 1024; char* lA1 = lA0 + 4096;
  char* lB0 = (char*)smB + wid * 1024; char* lB1 = lB0 + 4096;
  int wr = wid >> 1, wc = wid & 1, lr = lane & 15, lg = lane >> 4;
  const short* pA = smA + (wr * 64 + lr) * 32 + lg * 8;
  const short* pB = smB + (wc * 64 + lr) * 32 + lg * 8;
  f32x4 acc[4][4];
  const f32x4 fz = {0.f, 0.f, 0.f, 0.f};
  for (int i2 = 0; i2 < 4; ++i2) for (int j2 = 0; j2 < 4; ++j2) acc[i2][j2] = fz;
  for (int k0 = 0; k0 < DDIM; k0 += 32) {
    gld16(a0, lA0); gld16(a1, lA1); gld16(b0, lB0); gld16(b1, lB1);
    a0 += 32; a1 += 32; b0 += 32; b1 += 32;
    __syncthreads();
    bf16x8 af[4], bv[4];
#pragma unroll
    for (int mi = 0; mi < 4; ++mi) af[mi] = *(const bf16x8*)(pA + mi * 512);
#pragma unroll
    for (int ni = 0; ni < 4; ++ni) bv[ni] = *(const bf16x8*)(pB + ni * 512);
#pragma unroll
    for (int mi = 0; mi < 4; ++mi)
#pragma unroll
      for (int ni = 0; ni < 4; ++ni)
        acc[mi][ni] = __builtin_amdgcn_mfma_f32_16x16x32_bf16(af[mi], bv[ni], acc[mi][ni], 0, 0, 0);
    __syncthreads();
  }
#pragma unroll
  for (int mi = 0; mi < 4; ++mi) {
#pragma unroll
    for (int rg = 0; rg < 4; ++rg) {
      int gm = m0 + wr * 64 + mi * 16 + lg * 4 + rg;
      int bb = gm / PTOT;
      int i = gm - bb * PTOT;
      float* Mrow = M + (size_t)gm * PTOT;
#pragma unroll
      for (int ni = 0; ni < 4; ++ni) {
        int j = n0 + wc * 64 + ni * 16 + lr;
        if (j < PM1) {
          int q2 = j + (j >= i);
          Mrow[q2] = acc[mi][ni][rg] + att_b[j];
        }
      }
    }
  }
}

// ---------------- kernel 5: row softmax in place on M (+ optional bf16 copy) --
__global__ __launch_bounds__(256) void k_softmax(float* __restrict__ M,
                                                 short* __restrict__ Mbf) {
  __shared__ float red[8];
  float* pr = M + (size_t)blockIdx.x * PTOT;
  int t = threadIdx.x;
  bool has2 = (t < 348 - 256);              // 2784/8 = 348 chunks of 8
  float v0[8], v1[8];
  f32x4 a0 = *(const f32x4*)(pr + t * 8);
  f32x4 a1 = *(const f32x4*)(pr + t * 8 + 4);
  float mx = -3.0e38f;
#pragma unroll
  for (int e = 0; e < 4; ++e) {
    v0[e] = a0[e]; v0[4 + e] = a1[e];
    mx = fmaxf(mx, fmaxf(v0[e], v0[4 + e]));
  }
  if (has2) {
    f32x4 b0 = *(const f32x4*)(pr + (256 + t) * 8);
    f32x4 b1 = *(const f32x4*)(pr + (256 + t) * 8 + 4);
#pragma unroll
    for (int e = 0; e < 4; ++e) {
      v1[e] = b0[e]; v1[4 + e] = b1[e];
      mx = fmaxf(mx, fmaxf(v1[e], v1[4 + e]));
    }
  }
#pragma unroll
  for (int off = 32; off; off >>= 1) mx = fmaxf(mx, __shfl_xor(mx, off));
  if ((t & 63) == 0) red[t >> 6] = mx;
  __syncthreads();
  mx = fmaxf(fmaxf(red[0], red[1]), fmaxf(red[2], red[3]));
  float s = 0.f;
#pragma unroll
  for (int e = 0; e < 8; ++e) { v0[e] = __expf(v0[e] - mx); s += v0[e]; }
  if (has2) {
#pragma unroll
    for (int e = 0; e < 8; ++e) { v1[e] = __expf(v1[e] - mx); s += v1[e]; }
  }
#pragma unroll
  for (int off = 32; off; off >>= 1) s += __shfl_xor(s, off);
  if ((t & 63) == 0) red[4 + (t >> 6)] = s;
  __syncthreads();
  s = (red[4] + red[5]) + (red[6] + red[7]);
  float inv = 1.f / s;
  {
    f32x4 o0, o1; bf16x8 ob;
#pragma unroll
    for (int e = 0; e < 8; ++e) {
      float w = v0[e] * inv;
      if (e < 4) o0[e] = w; else o1[e - 4] = w;
      ob[e] = f2bf_rne(w);
    }
    *(f32x4*)(pr + t * 8) = o0;
    *(f32x4*)(pr + t * 8 + 4) = o1;
    if (Mbf) *(bf16x8*)(Mbf + (size_t)blockIdx.x * PTOT + t * 8) = ob;
  }
  if (has2) {
    f32x4 o0, o1; bf16x8 ob;
#pragma unroll
    for (int e = 0; e < 8; ++e) {
      float w = v1[e] * inv;
      if (e < 4) o0[e] = w; else o1[e - 4] = w;
      ob[e] = f2bf_rne(w);
    }
    *(f32x4*)(pr + (256 + t) * 8) = o0;
    *(f32x4*)(pr + (256 + t) * 8 + 4) = o1;
    if (Mbf) *(bf16x8*)(Mbf + (size_t)blockIdx.x * PTOT + (256 + t) * 8) = ob;
  }
}

// ---------------- kernel 6a: att_feats = Mbf @ bafT  (pure bf16, m97) ---------
__global__ __launch_bounds__(256) void k_attfeat_bf(
    const short* __restrict__ Mbf, const short* __restrict__ bafT,
    short* __restrict__ attf) {
  __shared__ short smA[128 * 32];
  __shared__ short smB[128 * 32];
  int wg = blockIdx.x;                       // 1936 = 8*22*11, divisible by 8
  int xcd = wg & 7, lin = wg >> 3;
  int wgid = xcd * 242 + lin;
  int bb = wgid / 242; int rem = wgid - bb * 242;
  int it = rem / 11, dt = rem - it * 11;     // d fastest -> A-panel L2 reuse
  int i0 = it * 128, d0 = dt * 128;
  int t = threadIdx.x, wid = t >> 6, lane = t & 63;
  int rowa = t >> 2, kga = t & 3;
  const short* a0 = Mbf + ((size_t)(bb * PTOT + i0 + rowa)) * PTOT + kga * 8;
  const short* a1 = a0 + (size_t)64 * PTOT;
  const short* b0 = bafT + ((size_t)(bb * DDIM + d0 + rowa)) * PTOT + kga * 8;
  const short* b1 = b0 + (size_t)64 * PTOT;
  char* lA0 = (char*)smA + wid * 1024; char* lA1 = lA0 + 4096;
  char* lB0 = (char*)smB + wid * 1024; char* lB1 = lB0 + 4096;
  int wr = wid >> 1, wc = wid & 1, lr = lane & 15, lg = lane >> 4;
  const short* pA = smA + (wr * 64 + lr) * 32 + lg * 8;
  const short* pB = smB + (wc * 64 + lr) * 32 + lg * 8;
  f32x4 acc[4][4];
  const f32x4 fz = {0.f, 0.f, 0.f, 0.f};
  for (int i2 = 0; i2 < 4; ++i2) for (int j2 = 0; j2 < 4; ++j2) acc[i2][j2] = fz;
  for (int k0 = 0; k0 < PTOT; k0 += 32) {
    gld16(a0, lA0); gld16(a1, lA1); gld16(b0, lB0); gld16(b1, lB1);
    a0 += 32; a1 += 32; b0 += 32; b1 += 32;
    __syncthreads();
    bf16x8 af[4], bv[4];
#pragma unroll
    for (int mi = 0; mi < 4; ++mi) af[mi] = *(const bf16x8*)(pA + mi * 512);
#pragma unroll
    for (int ni = 0; ni < 4; ++ni) bv[ni] = *(const bf16x8*)(pB + ni * 512);
#pragma unroll
    for (int mi = 0; mi < 4; ++mi)
#pragma unroll
      for (int ni = 0; ni < 4; ++ni)
        acc[mi][ni] = __builtin_amdgcn_mfma_f32_16x16x32_bf16(af[mi], bv[ni], acc[mi][ni], 0, 0, 0);
    __syncthreads();
  }
#pragma unroll
  for (int mi = 0; mi < 4; ++mi) {
#pragma unroll
    for (int rg = 0; rg < 4; ++rg) {
      int i = i0 + wr * 64 + mi * 16 + lg * 4 + rg;
      if (i < PTOT) {
        short* arow = attf + ((size_t)(bb * PTOT + i)) * DDIM + d0 + wc * 64;
#pragma unroll
        for (int ni = 0; ni < 4; ++ni) arow[ni * 16 + lr] = f2bf_rne(acc[mi][ni][rg]);
      }
    }
  }
}

// ---------------- kernel 6b: fallback (f32 A, reg-staged) ---------------------
__global__ __launch_bounds__(256) void k_attfeat_f32(
    const float* __restrict__ M, const short* __restrict__ bafT,
    short* __restrict__ attf) {
  __shared__ short smA[128 * 32];
  __shared__ short smB[128 * 32];
  int wg = blockIdx.x;
  int xcd = wg & 7, lin = wg >> 3;
  int wgid = xcd * 242 + lin;
  int bb = wgid / 242; int rem = wgid - bb * 242;
  int it = rem / 11, dt = rem - it * 11;
  int i0 = it * 128, d0 = dt * 128;
  int t = threadIdx.x, wid = t >> 6, lane = t & 63;
  int rowa = t >> 2, kga = t & 3;
  const float* sA0 = M + ((size_t)(bb * PTOT + i0 + rowa)) * PTOT + kga * 8;
  const float* sA1 = sA0 + (size_t)64 * PTOT;
  short* dA0 = smA + rowa * 32 + kga * 8;
  short* dA1 = dA0 + 64 * 32;
  const short* sB0 = bafT + ((size_t)(bb * DDIM + d0 + rowa)) * PTOT + kga * 8;
  const short* sB1 = sB0 + (size_t)64 * PTOT;
  char* lB0 = (char*)smB + wid * 1024; char* lB1 = lB0 + 4096;
  int wr = wid >> 1, wc = wid & 1, lr = lane & 15, lg = lane >> 4;
  const short* pA = smA + (wr * 64 + lr) * 32 + lg * 8;
  const short* pB = smB + (wc * 64 + lr) * 32 + lg * 8;
  f32x4 acc[4][4];
  const f32x4 fz = {0.f, 0.f, 0.f, 0.f};
  for (int i2 = 0; i2 < 4; ++i2) for (int j2 = 0; j2 < 4; ++j2) acc[i2][j2] = fz;
  for (int k0 = 0; k0 < PTOT; k0 += 32) {
    gld16(sB0, lB0); gld16(sB1, lB1);
    f32x4 u0 = *(const f32x4*)sA0;
    f32x4 u1 = *(const f32x4*)(sA0 + 4);
    f32x4 u2 = *(const f32x4*)sA1;
    f32x4 u3 = *(const f32x4*)(sA1 + 4);
    bf16x8 v0, v1;
#pragma unroll
    for (int e = 0; e < 4; ++e) {
      v0[e] = f2bf_trunc(u0[e]); v0[4 + e] = f2bf_trunc(u1[e]);
      v1[e] = f2bf_trunc(u2[e]); v1[4 + e] = f2bf_trunc(u3[e]);
    }
    *(bf16x8*)dA0 = v0;
    *(bf16x8*)dA1 = v1;
    sA0 += 32; sA1 += 32; sB0 += 32; sB1 += 32;
    __syncthreads();
    bf16x8 af[4], bv[4];
#pragma unroll
    for (int mi = 0; mi < 4; ++mi) af[mi] = *(const bf16x8*)(pA + mi * 512);
#pragma unroll
    for (int ni = 0; ni < 4; ++ni) bv[ni] = *(const bf16x8*)(pB + ni * 512);
#pragma unroll
    for (int mi = 0; mi < 4; ++mi)
#pragma unroll
      for (int ni = 0; ni < 4; ++ni)
        acc[mi][ni] = __builtin_amdgcn_mfma_f32_16x16x32_bf16(af[mi], bv[ni], acc[mi][ni], 0, 0, 0);
    __syncthreads();
  }
#pragma unroll
  for (int mi = 0; mi < 4; ++mi) {
#pragma unroll
    for (int rg = 0; rg < 4; ++rg) {
      int i = i0 + wr * 64 + mi * 16 + lg * 4 + rg;
      if (i < PTOT) {
        short* arow = attf + ((size_t)(bb * PTOT + i)) * DDIM + d0 + wc * 64;
#pragma unroll
        for (int ni = 0; ni < 4; ++ni) arow[ni * 16 + lr] = f2bf_rne(acc[mi][ni][rg]);
      }
    }
  }
}

// ---------------- kernel 7: heads GEMM + proposal assembly --------------------
__global__ __launch_bounds__(256) void k_head(
    const short* __restrict__ attf, const short* __restrict__ baf,
    const short* __restrict__ wbf, const float* __restrict__ bias80,
    const float* __restrict__ anch, float* __restrict__ out) {
  __shared__ short smA[64 * 32];
  __shared__ short smB[80 * 32];
  int r0 = blockIdx.x * 64;
  int t = threadIdx.x, wid = t >> 6, lane = t & 63;
  int rowa = t >> 2, kg = t & 3;
  const short* sA_att = attf + (size_t)(r0 + rowa) * DDIM + kg * 8;
  const short* sA_baf = baf + (size_t)(r0 + rowa) * DDIM + kg * 8;
  const short* sB0 = wbf + (size_t)rowa * KHEAD + kg * 8;
  const short* sB1 = wbf + (size_t)(64 + (t >> 2)) * KHEAD + (t & 3) * 8;
  char* lA = (char*)smA + wid * 1024;
  char* lB0 = (char*)smB + wid * 1024;
  char* lB1 = (char*)smB + 4096;
  int lr = lane & 15, lg = lane >> 4;
  const short* pA = smA + (wid * 16 + lr) * 32 + lg * 8;
  const short* pB = smB + lr * 32 + lg * 8;
  f32x4 acc[5];
  const f32x4 fz = {0.f, 0.f, 0.f, 0.f};
  for (int i2 = 0; i2 < 5; ++i2) acc[i2] = fz;
  for (int ks = 0; ks < 88; ++ks) {
    const short* sA = (ks < 44) ? (sA_att + ks * 32) : (sA_baf + (ks - 44) * 32);
    gld16(sA, lA);
    gld16(sB0 + ks * 32, lB0);
    if (t < 64) gld16(sB1 + ks * 32, lB1);
    __syncthreads();
    bf16x8 a = *(const bf16x8*)pA;
#pragma unroll
    for (int ni = 0; ni < 5; ++ni) {
      bf16x8 b = *(const bf16x8*)(pB + ni * 512);
      acc[ni] = __builtin_amdgcn_mfma_f32_16x16x32_bf16(a, b, acc[ni], 0, 0, 0);
    }
    __syncthreads();
  }
#pragma unroll
  for (int ni = 0; ni < 5; ++ni) {
#pragma unroll
    for (int rg = 0; rg < 4; ++rg) {
      int n = ni * 16 + lr;
      int i = wid * 16 + lg * 4 + rg;
      int rgl = r0 + i;
      int p = rgl % PTOT;
      float v = acc[ni][rg] + bias80[n];
      if (n < 2) {
        out[(size_t)rgl * 77 + n] = v;
      } else if (n == 2) {
        out[(size_t)rgl * 77 + 2] =
            (anch[(size_t)p * 77 + 2] + 1.f / (1.f + __expf(-v))) * 0.5f;
        out[(size_t)rgl * 77 + 3] = anch[(size_t)p * 77 + 3];
      } else if (n < 76) {
        out[(size_t)rgl * 77 + n + 1] = v + anch[(size_t)p * 77 + n + 1];
      }
    }
  }
}

extern "C" void kernel_launch(void* const* d_in, const int* in_sizes, int n_in,
                              void* d_out, int out_size, void* d_ws, size_t ws_size,
                              hipStream_t stream) {
  const float* x      = (const float*)d_in[0];
  const float* conv_w = (const float*)d_in[1];
  const float* conv_b = (const float*)d_in[2];
  const float* att_w  = (const float*)d_in[3];
  const float* att_b  = (const float*)d_in[4];
  const float* cls_w  = (const float*)d_in[5];
  const float* cls_b  = (const float*)d_in[6];
  const float* so_w   = (const float*)d_in[7];
  const float* so_b   = (const float*)d_in[8];
  const float* reg_w  = (const float*)d_in[9];
  const float* reg_b  = (const float*)d_in[10];
  const float* anchors= (const float*)d_in[11];
  const int*   cut_xs = (const int*)d_in[12];
  const unsigned char* invalid = (const unsigned char*)d_in[13];

  float* out_rp = (float*)d_out;
  float* Mmat = out_rp + (size_t)ROWS * 77;              // 1,714,944
  float* feat = Mmat + (size_t)ROWS * PTOT;              // + 62,005,248

  char* wsp = (char*)d_ws;
  short* baf    = (short*)wsp;                           // 62,717,952 B
  short* bafT   = (short*)(wsp + 62717952ULL);           // 62,717,952 B
  short* attw   = (short*)(wsp + 125435904ULL);          //  7,929,856 B
  short* wbf    = (short*)(wsp + 133365760ULL);          //    450,560 B
  float* bias80 = (float*)(wsp + 133816320ULL);          //        512 B
  short* attf   = (short*)(wsp + 133816832ULL);          // 62,717,952 B -> 196,534,784
  short* Mbf    = (short*)(wsp + 196534784ULL);          // (ROWS+64)*PTOT*2 = 124,366,848
  const size_t WS_NEED = 196534784ULL + 124366848ULL;    // 320,901,632 B

  bool fast = (ws_size >= WS_NEED);

  k_conv<<<224, 256, 0, stream>>>(x, conv_w, conv_b, feat);
  k_prep<<<2048, 256, 0, stream>>>(att_w, cls_w, so_w, reg_w, cls_b, so_b, reg_b,
                                   attw, wbf, bias80, Mmat);
  k_gather<<<dim3(44, 22, 8), 256, 0, stream>>>(feat, cut_xs, invalid, baf, bafT);
  k_scores<<<174 * 22, 256, 0, stream>>>(baf, attw, att_b, Mmat);
  k_softmax<<<ROWS, 256, 0, stream>>>(Mmat, fast ? Mbf : (short*)nullptr);
  if (fast)
    k_attfeat_bf<<<1936, 256, 0, stream>>>(Mbf, bafT, attf);
  else
    k_attfeat_f32<<<1936, 256, 0, stream>>>(Mmat, bafT, attf);
  k_head<<<348, 256, 0, stream>>>(attf, baf, wbf, bias80, anchors, out_rp);
}

// Round 3
// 807.027 us; speedup vs baseline: 1.0398x; 1.0381x over previous
//
#include <hip/hip_runtime.h>
#include <stdint.h>

#define PTOT 2784
#define PM1  2783
#define DDIM 1408
#define NB   8
#define ROWS 22272        // NB*PTOT
#define KHEAD 2816        // 2*DDIM
#define KP1  1536         // padded D (K of scores, N of attfeat)
#define PP   2816         // padded P (N of scores, K of attfeat)

typedef __attribute__((ext_vector_type(8))) short bf16x8;
typedef __attribute__((ext_vector_type(4))) float f32x4;

__device__ __forceinline__ short f2bf_rne(float x) {
    uint32_t u = __float_as_uint(x);
    u += 0x7fffu + ((u >> 16) & 1u);
    return (short)(u >> 16);
}

// async global->LDS, 16B per lane. lds dest = wave-uniform base + lane*16.
__device__ __forceinline__ void gld16(const void* g, void* l) {
    __builtin_amdgcn_global_load_lds(
        (const __attribute__((address_space(1))) void*)(uintptr_t)g,
        (__attribute__((address_space(3))) void*)(uint32_t)(uintptr_t)l,
        16, 0, 0);
}

// ---------------- kernel 1: 1x1 conv -> feat (f32, written to d_out) ----------
__global__ __launch_bounds__(256) void k_conv(
    const float* __restrict__ x, const float* __restrict__ w,
    const float* __restrict__ cb, float* __restrict__ feat) {
  __shared__ float xs[256 * 32];
  int b = blockIdx.x / 28;
  int t0 = (blockIdx.x % 28) * 32;
  int t = threadIdx.x;
  for (int i = t; i < 256 * 32; i += 256) {
    int c = i >> 5, pos = i & 31;
    int hw = t0 + pos;
    xs[i] = (hw < 880) ? x[((size_t)b * 256 + c) * 880 + hw] : 0.f;
  }
  __syncthreads();
  int o = t & 63, g = t >> 6;
  float acc[8];
#pragma unroll
  for (int pp = 0; pp < 8; ++pp) acc[pp] = cb[o];
  const float* wr = w + o * 256;
  for (int c = 0; c < 256; ++c) {
    float wv = wr[c];
#pragma unroll
    for (int pp = 0; pp < 8; ++pp) acc[pp] += wv * xs[c * 32 + g + pp * 4];
  }
#pragma unroll
  for (int pp = 0; pp < 8; ++pp) {
    int hw = t0 + g + pp * 4;
    if (hw < 880) feat[((size_t)b * 64 + o) * 880 + hw] = acc[pp];
  }
}

// ---------------- kernel 2: prep (bf16 weights zero-padded, bias, M diag) -----
__global__ __launch_bounds__(256) void k_prep(
    const float* __restrict__ att_w, const float* __restrict__ cls_w,
    const float* __restrict__ so_w, const float* __restrict__ reg_w,
    const float* __restrict__ cls_b, const float* __restrict__ so_b,
    const float* __restrict__ reg_b,
    short* __restrict__ attw, short* __restrict__ wbf,
    float* __restrict__ bias80, float* __restrict__ M) {
  const int64_t n_attw = (int64_t)PP * KP1;        // [2816][1536]
  const int64_t n_w = 80 * (int64_t)KHEAD;
  const int64_t total = n_attw + n_w + 80 + ROWS;
  for (int64_t i = (int64_t)blockIdx.x * 256 + threadIdx.x; i < total;
       i += (int64_t)gridDim.x * 256) {
    if (i < n_attw) {
      int j = (int)(i / KP1), k = (int)(i - (int64_t)j * KP1);
      float v = (j < PM1 && k < DDIM) ? att_w[(size_t)j * DDIM + k] : 0.f;
      attw[i] = f2bf_rne(v);
    } else if (i < n_attw + n_w) {
      int64_t ii = i - n_attw;
      int n = (int)(ii / KHEAD), k = (int)(ii - (int64_t)n * KHEAD);
      float v = 0.f;
      if (n < 2) v = cls_w[n * KHEAD + k];
      else if (n == 2) v = so_w[k];
      else if (n < 76) v = reg_w[(size_t)(n - 3) * KHEAD + k];
      wbf[ii] = f2bf_rne(v);
    } else if (i < n_attw + n_w + 80) {
      int n = (int)(i - n_attw - n_w);
      float v = 0.f;
      if (n < 2) v = cls_b[n];
      else if (n == 2) v = so_b[0];
      else if (n < 76) v = reg_b[n - 3];
      bias80[n] = v;
    } else {
      int r = (int)(i - n_attw - n_w - 80);
      int p = r % PTOT;
      M[(size_t)r * PTOT + p] = -1e30f;   // softmax -> exact 0 on diagonal
    }
  }
}

// ---------------- kernel 3: gather rois -> baf [22272][1408] bf16 and ---------
// ----------------            bafT [8][1536][2816] bf16 (pads zeroed) ----------
__global__ __launch_bounds__(256) void k_gather(
    const float* __restrict__ feat, const int* __restrict__ cutx,
    const unsigned char* __restrict__ inval,
    short* __restrict__ baf, short* __restrict__ bafT) {
  int p0 = blockIdx.x * 64, d0 = blockIdx.y * 64, b = blockIdx.z;
  __shared__ short tile[64][72];
  int t = threadIdx.x;
  for (int i = t; i < 64 * 64; i += 256) {
    int pl = i >> 6, dl = i & 63;
    int p = p0 + pl, d = d0 + dl;
    float v = 0.f;
    if (p < PTOT && d < DDIM) {
      int c = d / 22, h = d - c * 22;
      if (!inval[p * 22 + h]) {
        int xc = cutx[p * 22 + h];
        v = feat[(((size_t)b * 64 + c) * 22 + h) * 40 + xc];
      }
    }
    tile[pl][dl] = f2bf_rne(v);
  }
  __syncthreads();
  if (d0 < DDIM) {
    for (int u = t; u < 512; u += 256) {   // baf rows: coalesced along d
      int pl = u >> 3, dg = u & 7;
      int p = p0 + pl;
      if (p < PTOT) {
        bf16x8 v;
#pragma unroll
        for (int e = 0; e < 8; ++e) v[e] = tile[pl][dg * 8 + e];
        *(bf16x8*)&baf[((size_t)b * PTOT + p) * DDIM + d0 + dg * 8] = v;
      }
    }
  }
  for (int u = t; u < 512; u += 256) {     // bafT rows: coalesced along p
    int dl = u >> 3, pg = u & 7;
    bf16x8 v;
#pragma unroll
    for (int e = 0; e < 8; ++e) v[e] = tile[pg * 8 + e][dl];
    *(bf16x8*)&bafT[((size_t)b * KP1 + d0 + dl) * PP + p0 + pg * 8] = v;
  }
}

// =============== 256x256 8-wave counted-vmcnt GEMM (T2+T3+T4+T5) ==============
// BK=32, 4 K-tile LDS buffers (4 x 32KB = 128KB), depth-3 prefetch, vmcnt(8)
// steady. LDS swizzle f(x)=x^(((x>>7)&3)<<4) on reads; staging pre-swizzles the
// per-lane GLOBAL source so the gld16 LDS dest stays linear (rule #21).
#define VMW(N) asm volatile("s_waitcnt vmcnt(" #N ")" ::: "memory")

#define TILE_BODY(T_, STAGE_, VM_)                                             \
  {                                                                            \
    const char* bufc_ = sm + (((T_) & 3) << 15);                               \
    bf16x8 b_[4], aa_[4];                                                      \
    _Pragma("unroll")                                                          \
    for (int n = 0; n < 4; ++n)                                                \
      b_[n] = *(const bf16x8*)(bufc_ + offB[n]);                               \
    _Pragma("unroll")                                                          \
    for (int m = 0; m < 4; ++m)                                                \
      aa_[m] = *(const bf16x8*)(bufc_ + offA[m]);                              \
    if (STAGE_) {                                                              \
      char* nb_ = sm + ((((T_) + 3) & 3) << 15);                               \
      gld16(gsrc[0] + (size_t)((T_) + 3) * 64, nb_ + dst[0]);                  \
      gld16(gsrc[1] + (size_t)((T_) + 3) * 64, nb_ + dst[1]);                  \
    }                                                                          \
    __builtin_amdgcn_s_barrier();                                              \
    asm volatile("s_waitcnt lgkmcnt(0)" ::: "memory");                         \
    __builtin_amdgcn_sched_barrier(0);                                         \
    __builtin_amdgcn_s_setprio(1);                                             \
    _Pragma("unroll")                                                          \
    for (int m = 0; m < 4; ++m)                                                \
      _Pragma("unroll")                                                        \
      for (int n = 0; n < 4; ++n)                                              \
        acc[m][n] = __builtin_amdgcn_mfma_f32_16x16x32_bf16(aa_[m], b_[n],     \
                                                        acc[m][n], 0, 0, 0);   \
    __builtin_amdgcn_s_setprio(0);                                             \
    __builtin_amdgcn_s_barrier();                                              \
    _Pragma("unroll")                                                          \
    for (int m = 0; m < 4; ++m)                                                \
      aa_[m] = *(const bf16x8*)(bufc_ + offA[4 + m]);                          \
    if (STAGE_) {                                                              \
      char* nb_ = sm + ((((T_) + 3) & 3) << 15);                               \
      gld16(gsrc[2] + (size_t)((T_) + 3) * 64, nb_ + dst[2]);                  \
      gld16(gsrc[3] + (size_t)((T_) + 3) * 64, nb_ + dst[3]);                  \
    }                                                                          \
    __builtin_amdgcn_s_barrier();                                              \
    asm volatile("s_waitcnt lgkmcnt(0)" ::: "memory");                         \
    __builtin_amdgcn_sched_barrier(0);                                         \
    __builtin_amdgcn_s_setprio(1);                                             \
    _Pragma("unroll")                                                          \
    for (int m = 0; m < 4; ++m)                                                \
      _Pragma("unroll")                                                        \
      for (int n = 0; n < 4; ++n)                                              \
        acc[4 + m][n] = __builtin_amdgcn_mfma_f32_16x16x32_bf16(aa_[m], b_[n], \
                                                    acc[4 + m][n], 0, 0, 0);   \
    __builtin_amdgcn_s_setprio(0);                                             \
    if ((VM_) == 8) VMW(8);                                                    \
    else if ((VM_) == 4) VMW(4);                                               \
    else if ((VM_) == 0) VMW(0);                                               \
    __builtin_amdgcn_s_barrier();                                              \
  }

// EPI 0: scores  A=baf[22272][1408](K-pad via attw zeros) B=attw[2816][1536]
//        -> scatter f32 into M with diagonal shift, +att_b
// EPI 1: attfeat A=Mbf[.][2784](K-pad via bafT zeros)     B=bafT[8][1536][2816]
//        -> attf[8][2784][1408] bf16
template<int EPI>
__global__ __launch_bounds__(512, 2) void k_gemm256(
    const short* __restrict__ Ag, const short* __restrict__ Bg,
    const float* __restrict__ att_b, float* __restrict__ Mout,
    short* __restrict__ attf) {
  constexpr int NT  = (EPI == 0) ? (KP1 / 32) : (PP / 32);   // 48 / 88
  constexpr int LDA = (EPI == 0) ? DDIM : PTOT;              // elements
  constexpr int LDB = (EPI == 0) ? KP1 : PP;
  __shared__ char sm[131072];

  int wg = blockIdx.x;
  int m0, n0, bb = 0;
  if (EPI == 0) {           // 957 tiles = 87 x 11 ; bijective xcd swizzle q=119 r=5
    int xcd = wg & 7, lin = wg >> 3;
    int wgid = (xcd < 5) ? xcd * 120 + lin : 5 * 120 + (xcd - 5) * 119 + lin;
    int it = wgid / 11, nt = wgid - it * 11;
    m0 = it * 256; n0 = nt * 256;
  } else {                  // 528 = 8 x 66
    int xcd = wg & 7, lin = wg >> 3;
    int wgid = xcd * 66 + lin;
    bb = wgid / 66; int rem = wgid - bb * 66;
    int it = rem / 6, dt = rem - it * 6;
    m0 = it * 256; n0 = dt * 256;
  }
  const short* Abase = Ag + (EPI == 0 ? (size_t)0 : (size_t)bb * PTOT * LDA);
  const short* Bbase = Bg + (EPI == 0 ? (size_t)0 : (size_t)bb * KP1 * LDB);

  int T = threadIdx.x, w = T >> 6, l = T & 63;
  int lr = l & 15, lg = l >> 4;
  int wm = w >> 2, wn = w & 3;

  // staging: 4 gld16/tile/wave; pre-swizzled global sources, linear LDS dest
  const char* gsrc[4];
  int dst[4];
#pragma unroll
  for (int i = 0; i < 4; ++i) {
    int region = i >> 1, chunk = i & 1;
    int o = chunk * 8192 + w * 1024 + l * 16;
    int row = o >> 6;
    int colb = (o & 63) ^ (((o >> 7) & 3) << 4);
    const short* base = (region == 0) ? (Abase + (size_t)(m0 + row) * LDA)
                                      : (Bbase + (size_t)(n0 + row) * LDB);
    gsrc[i] = (const char*)base + colb;
    dst[i] = region * 16384 + o;
  }
  // swizzled read offsets (per-thread constants)
  int offA[8], offB[4];
#pragma unroll
  for (int m = 0; m < 8; ++m) {
    int x = (wm * 128 + m * 16 + lr) * 64 + lg * 16;
    offA[m] = x ^ (((x >> 7) & 3) << 4);
  }
#pragma unroll
  for (int n = 0; n < 4; ++n) {
    int x = (wn * 64 + n * 16 + lr) * 64 + lg * 16;
    offB[n] = 16384 + (x ^ (((x >> 7) & 3) << 4));
  }

  f32x4 acc[8][4];
  const f32x4 fz = {0.f, 0.f, 0.f, 0.f};
#pragma unroll
  for (int m = 0; m < 8; ++m)
#pragma unroll
    for (int n = 0; n < 4; ++n) acc[m][n] = fz;

  // prologue: stage K-tiles 0,1,2 into buffers 0,1,2
#pragma unroll
  for (int pt = 0; pt < 3; ++pt)
#pragma unroll
    for (int i = 0; i < 4; ++i)
      gld16(gsrc[i] + (size_t)pt * 64, sm + (pt << 15) + dst[i]);
  VMW(8);                                  // tile 0 landed (12 - 8 oldest)
  __builtin_amdgcn_s_barrier();

  int t = 0;
  for (; t < NT - 3; ++t) { TILE_BODY(t, 1, 8); }
  TILE_BODY(t, 0, 4); ++t;
  TILE_BODY(t, 0, 0); ++t;
  TILE_BODY(t, 0, -1);

  // epilogue
  if (EPI == 0) {
#pragma unroll
    for (int m = 0; m < 8; ++m) {
#pragma unroll
      for (int rg = 0; rg < 4; ++rg) {
        int gmi = m0 + wm * 128 + m * 16 + lg * 4 + rg;
        int i = gmi % PTOT;
        float* Mrow = Mout + (size_t)gmi * PTOT;
#pragma unroll
        for (int n = 0; n < 4; ++n) {
          int j = n0 + wn * 64 + n * 16 + lr;
          if (j < PM1) {
            int q2 = j + (j >= i);
            Mrow[q2] = acc[m][n][rg] + att_b[j];
          }
        }
      }
    }
  } else {
#pragma unroll
    for (int m = 0; m < 8; ++m) {
#pragma unroll
      for (int rg = 0; rg < 4; ++rg) {
        int i = m0 + wm * 128 + m * 16 + lg * 4 + rg;
        if (i < PTOT) {
          short* arow = attf + ((size_t)(bb * PTOT + i)) * DDIM;
#pragma unroll
          for (int n = 0; n < 4; ++n) {
            int d = n0 + wn * 64 + n * 16 + lr;
            if (d < DDIM) arow[d] = f2bf_rne(acc[m][n][rg]);
          }
        }
      }
    }
  }
}

// ---------------- kernel 5: row softmax in place on M + bf16 copy -------------
__global__ __launch_bounds__(256) void k_softmax(float* __restrict__ M,
                                                 short* __restrict__ Mbf) {
  __shared__ float red[8];
  float* pr = M + (size_t)blockIdx.x * PTOT;
  int t = threadIdx.x;
  bool has2 = (t < 348 - 256);              // 2784/8 = 348 chunks of 8
  float v0[8], v1[8];
  f32x4 a0 = *(const f32x4*)(pr + t * 8);
  f32x4 a1 = *(const f32x4*)(pr + t * 8 + 4);
  float mx = -3.0e38f;
#pragma unroll
  for (int e = 0; e < 4; ++e) {
    v0[e] = a0[e]; v0[4 + e] = a1[e];
    mx = fmaxf(mx, fmaxf(v0[e], v0[4 + e]));
  }
  if (has2) {
    f32x4 b0 = *(const f32x4*)(pr + (256 + t) * 8);
    f32x4 b1 = *(const f32x4*)(pr + (256 + t) * 8 + 4);
#pragma unroll
    for (int e = 0; e < 4; ++e) {
      v1[e] = b0[e]; v1[4 + e] = b1[e];
      mx = fmaxf(mx, fmaxf(v1[e], v1[4 + e]));
    }
  }
#pragma unroll
  for (int off = 32; off; off >>= 1) mx = fmaxf(mx, __shfl_xor(mx, off));
  if ((t & 63) == 0) red[t >> 6] = mx;
  __syncthreads();
  mx = fmaxf(fmaxf(red[0], red[1]), fmaxf(red[2], red[3]));
  float s = 0.f;
#pragma unroll
  for (int e = 0; e < 8; ++e) { v0[e] = __expf(v0[e] - mx); s += v0[e]; }
  if (has2) {
#pragma unroll
    for (int e = 0; e < 8; ++e) { v1[e] = __expf(v1[e] - mx); s += v1[e]; }
  }
#pragma unroll
  for (int off = 32; off; off >>= 1) s += __shfl_xor(s, off);
  if ((t & 63) == 0) red[4 + (t >> 6)] = s;
  __syncthreads();
  s = (red[4] + red[5]) + (red[6] + red[7]);
  float inv = 1.f / s;
  {
    f32x4 o0, o1; bf16x8 ob;
#pragma unroll
    for (int e = 0; e < 8; ++e) {
      float wv = v0[e] * inv;
      if (e < 4) o0[e] = wv; else o1[e - 4] = wv;
      ob[e] = f2bf_rne(wv);
    }
    *(f32x4*)(pr + t * 8) = o0;
    *(f32x4*)(pr + t * 8 + 4) = o1;
    *(bf16x8*)(Mbf + (size_t)blockIdx.x * PTOT + t * 8) = ob;
  }
  if (has2) {
    f32x4 o0, o1; bf16x8 ob;
#pragma unroll
    for (int e = 0; e < 8; ++e) {
      float wv = v1[e] * inv;
      if (e < 4) o0[e] = wv; else o1[e - 4] = wv;
      ob[e] = f2bf_rne(wv);
    }
    *(f32x4*)(pr + (256 + t) * 8) = o0;
    *(f32x4*)(pr + (256 + t) * 8 + 4) = o1;
    *(bf16x8*)(Mbf + (size_t)blockIdx.x * PTOT + (256 + t) * 8) = ob;
  }
}

// ---------------- kernel 7: heads GEMM + proposal assembly --------------------
__global__ __launch_bounds__(256) void k_head(
    const short* __restrict__ attf, const short* __restrict__ baf,
    const short* __restrict__ wbf, const float* __restrict__ bias80,
    const float* __restrict__ anch, float* __restrict__ out) {
  __shared__ short smA[64 * 32];
  __shared__ short smB[80 * 32];
  int r0 = blockIdx.x * 64;
  int t = threadIdx.x, wid = t >> 6, lane = t & 63;
  int rowa = t >> 2, kg = t & 3;
  const short* sA_att = attf + (size_t)(r0 + rowa) * DDIM + kg * 8;
  const short* sA_baf = baf + (size_t)(r0 + rowa) * DDIM + kg * 8;
  const short* sB0 = wbf + (size_t)rowa * KHEAD + kg * 8;
  const short* sB1 = wbf + (size_t)(64 + (t >> 2)) * KHEAD + (t & 3) * 8;
  char* lA = (char*)smA + wid * 1024;
  char* lB0 = (char*)smB + wid * 1024;
  char* lB1 = (char*)smB + 4096;
  int lr = lane & 15, lg = lane >> 4;
  const short* pA = smA + (wid * 16 + lr) * 32 + lg * 8;
  const short* pB = smB + lr * 32 + lg * 8;
  f32x4 acc[5];
  const f32x4 fz = {0.f, 0.f, 0.f, 0.f};
  for (int i2 = 0; i2 < 5; ++i2) acc[i2] = fz;
  for (int ks = 0; ks < 88; ++ks) {
    const short* sA = (ks < 44) ? (sA_att + ks * 32) : (sA_baf + (ks - 44) * 32);
    gld16(sA, lA);
    gld16(sB0 + ks * 32, lB0);
    if (t < 64) gld16(sB1 + ks * 32, lB1);
    __syncthreads();
    bf16x8 a = *(const bf16x8*)pA;
#pragma unroll
    for (int ni = 0; ni < 5; ++ni) {
      bf16x8 b = *(const bf16x8*)(pB + ni * 512);
      acc[ni] = __builtin_amdgcn_mfma_f32_16x16x32_bf16(a, b, acc[ni], 0, 0, 0);
    }
    __syncthreads();
  }
#pragma unroll
  for (int ni = 0; ni < 5; ++ni) {
#pragma unroll
    for (int rg = 0; rg < 4; ++rg) {
      int n = ni * 16 + lr;
      int i = wid * 16 + lg * 4 + rg;
      int rgl = r0 + i;
      int p = rgl % PTOT;
      float v = acc[ni][rg] + bias80[n];
      if (n < 2) {
        out[(size_t)rgl * 77 + n] = v;
      } else if (n == 2) {
        out[(size_t)rgl * 77 + 2] =
            (anch[(size_t)p * 77 + 2] + 1.f / (1.f + __expf(-v))) * 0.5f;
        out[(size_t)rgl * 77 + 3] = anch[(size_t)p * 77 + 3];
      } else if (n < 76) {
        out[(size_t)rgl * 77 + n + 1] = v + anch[(size_t)p * 77 + n + 1];
      }
    }
  }
}

extern "C" void kernel_launch(void* const* d_in, const int* in_sizes, int n_in,
                              void* d_out, int out_size, void* d_ws, size_t ws_size,
                              hipStream_t stream) {
  const float* x      = (const float*)d_in[0];
  const float* conv_w = (const float*)d_in[1];
  const float* conv_b = (const float*)d_in[2];
  const float* att_w  = (const float*)d_in[3];
  const float* att_b  = (const float*)d_in[4];
  const float* cls_w  = (const float*)d_in[5];
  const float* cls_b  = (const float*)d_in[6];
  const float* so_w   = (const float*)d_in[7];
  const float* so_b   = (const float*)d_in[8];
  const float* reg_w  = (const float*)d_in[9];
  const float* reg_b  = (const float*)d_in[10];
  const float* anchors= (const float*)d_in[11];
  const int*   cut_xs = (const int*)d_in[12];
  const unsigned char* invalid = (const unsigned char*)d_in[13];

  float* out_rp = (float*)d_out;
  float* Mmat = out_rp + (size_t)ROWS * 77;
  float* feat = Mmat + (size_t)ROWS * PTOT;

  // workspace layout (319,639,040 B total; attw/attf lifetimes disjoint -> shared)
  char* wsp = (char*)d_ws;
  short* baf    = (short*)wsp;                          // 62,717,952 + 256 pad
  short* bafT   = (short*)(wsp + 62718208ULL);          // 8*1536*2816*2 = 69,206,016
  short* Mbf    = (short*)(wsp + 131924224ULL);         // 22304*2784*2 +pad = 124,545,792
  short* wbf    = (short*)(wsp + 256470016ULL);         // 450,560
  float* bias80 = (float*)(wsp + 256920576ULL);         // 512
  short* attw   = (short*)(wsp + 256921088ULL);         // 8,650,752 (then reused:)
  short* attf   = (short*)(wsp + 256921088ULL);         // 62,717,952

  k_conv<<<224, 256, 0, stream>>>(x, conv_w, conv_b, feat);
  k_prep<<<2048, 256, 0, stream>>>(att_w, cls_w, so_w, reg_w, cls_b, so_b, reg_b,
                                   attw, wbf, bias80, Mmat);
  k_gather<<<dim3(44, 24, 8), 256, 0, stream>>>(feat, cut_xs, invalid, baf, bafT);
  k_gemm256<0><<<957, 512, 0, stream>>>(baf, attw, att_b, Mmat, (short*)nullptr);
  k_softmax<<<ROWS, 256, 0, stream>>>(Mmat, Mbf);
  k_gemm256<1><<<528, 512, 0, stream>>>(Mbf, bafT, (const float*)nullptr,
                                        (float*)nullptr, attf);
  k_head<<<348, 256, 0, stream>>>(attf, baf, wbf, bias80, anchors, out_rp);
}

// Round 4
// 798.736 us; speedup vs baseline: 1.0506x; 1.0104x over previous
//
#include <hip/hip_runtime.h>
#include <stdint.h>

#define PTOT 2784
#define PM1  2783
#define DDIM 1408
#define NB   8
#define ROWS 22272        // NB*PTOT
#define KHEAD 2816        // 2*DDIM
#define MROW 2816         // Mbf padded rows per batch (11*256)
#define BTROWS 1536       // bafT padded d-rows per batch (6*256)

typedef __attribute__((ext_vector_type(8))) short bf16x8;
typedef __attribute__((ext_vector_type(4))) float f32x4;

__device__ __forceinline__ short f2bf_rne(float x) {
    uint32_t u = __float_as_uint(x);
    u += 0x7fffu + ((u >> 16) & 1u);
    return (short)(u >> 16);
}

// async global->LDS, 16B per lane. lds dest = wave-uniform base + lane*16.
__device__ __forceinline__ void gld16(const void* g, void* l) {
    __builtin_amdgcn_global_load_lds(
        (const __attribute__((address_space(1))) void*)(uintptr_t)g,
        (__attribute__((address_space(3))) void*)(uint32_t)(uintptr_t)l,
        16, 0, 0);
}

// ---------------- kernel 1: 1x1 conv -> feat (f32, written to d_out) ----------
__global__ __launch_bounds__(256) void k_conv(
    const float* __restrict__ x, const float* __restrict__ w,
    const float* __restrict__ cb, float* __restrict__ feat) {
  __shared__ float xs[256 * 32];
  int b = blockIdx.x / 28;
  int t0 = (blockIdx.x % 28) * 32;
  int t = threadIdx.x;
  for (int i = t; i < 256 * 32; i += 256) {
    int c = i >> 5, pos = i & 31;
    int hw = t0 + pos;
    xs[i] = (hw < 880) ? x[((size_t)b * 256 + c) * 880 + hw] : 0.f;
  }
  __syncthreads();
  int o = t & 63, g = t >> 6;
  float acc[8];
#pragma unroll
  for (int pp = 0; pp < 8; ++pp) acc[pp] = cb[o];
  const float* wr = w + o * 256;
  for (int c = 0; c < 256; ++c) {
    float wv = wr[c];
#pragma unroll
    for (int pp = 0; pp < 8; ++pp) acc[pp] += wv * xs[c * 32 + g + pp * 4];
  }
#pragma unroll
  for (int pp = 0; pp < 8; ++pp) {
    int hw = t0 + g + pp * 4;
    if (hw < 880) feat[((size_t)b * 64 + o) * 880 + hw] = acc[pp];
  }
}

// ---------------- kernel 2: prep (bf16 weights, bias, M diag) -----------------
__global__ __launch_bounds__(256) void k_prep(
    const float* __restrict__ att_w, const float* __restrict__ cls_w,
    const float* __restrict__ so_w, const float* __restrict__ reg_w,
    const float* __restrict__ cls_b, const float* __restrict__ so_b,
    const float* __restrict__ reg_b,
    short* __restrict__ attw, short* __restrict__ wbf,
    float* __restrict__ bias80, float* __restrict__ M) {
  const int64_t n_attw = (int64_t)2816 * DDIM;     // attw[2816][1408], rows>=2783 zero
  const int64_t n_w = 80 * (int64_t)KHEAD;
  const int64_t total = n_attw + n_w + 80 + ROWS;
  for (int64_t i = (int64_t)blockIdx.x * 256 + threadIdx.x; i < total;
       i += (int64_t)gridDim.x * 256) {
    if (i < n_attw) {
      int j = (int)(i / DDIM), k = (int)(i - (int64_t)j * DDIM);
      float v = (j < PM1) ? att_w[(size_t)j * DDIM + k] : 0.f;
      attw[i] = f2bf_rne(v);
    } else if (i < n_attw + n_w) {
      int64_t ii = i - n_attw;
      int n = (int)(ii / KHEAD), k = (int)(ii - (int64_t)n * KHEAD);
      float v = 0.f;
      if (n < 2) v = cls_w[n * KHEAD + k];
      else if (n == 2) v = so_w[k];
      else if (n < 76) v = reg_w[(size_t)(n - 3) * KHEAD + k];
      wbf[ii] = f2bf_rne(v);
    } else if (i < n_attw + n_w + 80) {
      int n = (int)(i - n_attw - n_w);
      float v = 0.f;
      if (n < 2) v = cls_b[n];
      else if (n == 2) v = so_b[0];
      else if (n < 76) v = reg_b[n - 3];
      bias80[n] = v;
    } else {
      int r = (int)(i - n_attw - n_w - 80);
      int p = r % PTOT;
      M[(size_t)r * PTOT + p] = -1e30f;   // softmax -> exact 0 on diagonal
    }
  }
}

// ---------------- kernel 3: gather rois -> baf [22272][1408] bf16 and ---------
// ----------------            bafT [8][1536][2784] bf16 (d-pad rows zeroed) ----
__global__ __launch_bounds__(256) void k_gather(
    const float* __restrict__ feat, const int* __restrict__ cutx,
    const unsigned char* __restrict__ inval,
    short* __restrict__ baf, short* __restrict__ bafT) {
  int p0 = blockIdx.x * 64, d0 = blockIdx.y * 64, b = blockIdx.z;
  __shared__ short tile[64][72];
  int t = threadIdx.x;
  for (int i = t; i < 64 * 64; i += 256) {
    int pl = i >> 6, dl = i & 63;
    int p = p0 + pl, d = d0 + dl;
    float v = 0.f;
    if (p < PTOT && d < DDIM) {
      int c = d / 22, h = d - c * 22;
      if (!inval[p * 22 + h]) {
        int xc = cutx[p * 22 + h];
        v = feat[(((size_t)b * 64 + c) * 22 + h) * 40 + xc];
      }
    }
    tile[pl][dl] = f2bf_rne(v);
  }
  __syncthreads();
  if (d0 < DDIM) {
    for (int u = t; u < 512; u += 256) {   // baf rows: coalesced along d
      int pl = u >> 3, dg = u & 7;
      int p = p0 + pl;
      if (p < PTOT) {
        bf16x8 v;
#pragma unroll
        for (int e = 0; e < 8; ++e) v[e] = tile[pl][dg * 8 + e];
        *(bf16x8*)&baf[((size_t)b * PTOT + p) * DDIM + d0 + dg * 8] = v;
      }
    }
  }
  for (int u = t; u < 512; u += 256) {     // bafT rows: coalesced along p
    int dl = u >> 3, pg = u & 7;
    int pbase = p0 + pg * 8;
    if (pbase + 7 < PTOT) {
      bf16x8 v;
#pragma unroll
      for (int e = 0; e < 8; ++e) v[e] = tile[pg * 8 + e][dl];
      *(bf16x8*)&bafT[((size_t)b * BTROWS + d0 + dl) * PTOT + pbase] = v;
    }
  }
}

// =============== 256x256 8-wave counted-vmcnt GEMM ============================
// BK=32, 4 K-tile LDS buffers (128KB), depth-3 prefetch, vmcnt(8) steady,
// ONE barrier per K-tile. LDS read swizzle f(x)=x^(((x>>7)&3)<<4); staging
// pre-swizzles the per-lane GLOBAL source, LDS dest stays linear (rule 21).
// Grid order: it-fastest within nt-groups per XCD -> B-panel L2-resident,
// A-panel reused across the nt-group while L2-live (L3 traffic ~4x lower).
#define VMW(N) asm volatile("s_waitcnt vmcnt(" #N ")" ::: "memory")

#define TILE_BODY(T_, STAGE_, VM_)                                             \
  {                                                                            \
    const char* bufc_ = sm + (((T_) & 3) << 15);                               \
    char* nb_ = sm + ((((T_) + 3) & 3) << 15);                                 \
    bf16x8 b_[4], aa_[4];                                                      \
    _Pragma("unroll") for (int n = 0; n < 4; ++n)                              \
      b_[n] = *(const bf16x8*)(bufc_ + offB[n]);                               \
    _Pragma("unroll") for (int m = 0; m < 4; ++m)                              \
      aa_[m] = *(const bf16x8*)(bufc_ + offA[m]);                              \
    if (STAGE_) {                                                              \
      gld16(gsrc[0] + (size_t)((T_) + 3) * 64, nb_ + dst[0]);                  \
      gld16(gsrc[1] + (size_t)((T_) + 3) * 64, nb_ + dst[1]);                  \
    }                                                                          \
    asm volatile("s_waitcnt lgkmcnt(0)" ::: "memory");                         \
    __builtin_amdgcn_sched_barrier(0);                                         \
    __builtin_amdgcn_s_setprio(1);                                             \
    _Pragma("unroll") for (int m = 0; m < 4; ++m)                              \
      _Pragma("unroll") for (int n = 0; n < 4; ++n)                            \
        acc[m][n] = __builtin_amdgcn_mfma_f32_16x16x32_bf16(aa_[m], b_[n],     \
                                                        acc[m][n], 0, 0, 0);   \
    __builtin_amdgcn_s_setprio(0);                                             \
    _Pragma("unroll") for (int m = 0; m < 4; ++m)                              \
      aa_[m] = *(const bf16x8*)(bufc_ + offA[4 + m]);                          \
    if (STAGE_) {                                                              \
      gld16(gsrc[2] + (size_t)((T_) + 3) * 64, nb_ + dst[2]);                  \
      gld16(gsrc[3] + (size_t)((T_) + 3) * 64, nb_ + dst[3]);                  \
    }                                                                          \
    asm volatile("s_waitcnt lgkmcnt(0)" ::: "memory");                         \
    __builtin_amdgcn_sched_barrier(0);                                         \
    __builtin_amdgcn_s_setprio(1);                                             \
    _Pragma("unroll") for (int m = 0; m < 4; ++m)                              \
      _Pragma("unroll") for (int n = 0; n < 4; ++n)                            \
        acc[4 + m][n] = __builtin_amdgcn_mfma_f32_16x16x32_bf16(aa_[m], b_[n], \
                                                    acc[4 + m][n], 0, 0, 0);   \
    __builtin_amdgcn_s_setprio(0);                                             \
    if ((VM_) == 8) VMW(8);                                                    \
    else if ((VM_) == 4) VMW(4);                                               \
    else if ((VM_) == 0) VMW(0);                                               \
    __builtin_amdgcn_s_barrier();                                              \
  }

// EPI 0: scores  A=baf[22272][1408] B=attw[2816][1408] K=1408
//        -> scatter f32 into M with diagonal shift, +att_b
// EPI 1: attfeat A=Mbf[8][2816][2784] B=bafT[8][1536][2784] K=2784
//        -> attf[8][2784][1408] bf16
template<int EPI>
__global__ __launch_bounds__(512, 2) void k_gemm256(
    const short* __restrict__ Ag, const short* __restrict__ Bg,
    const float* __restrict__ att_b, float* __restrict__ Mout,
    short* __restrict__ attf) {
  constexpr int NT  = (EPI == 0) ? 44 : 87;     // K/32, exact
  constexpr int LDAe = (EPI == 0) ? DDIM : PTOT;
  constexpr int LDBe = (EPI == 0) ? DDIM : PTOT;
  __shared__ char sm[131072];

  int wg = blockIdx.x;
  int m0, n0, bb = 0;
  if (EPI == 0) {
    // 957 blocks; bijective xcd chunk (q=119,r=5); nt-triples, it-fastest
    int xcd = wg & 7, lin = wg >> 3;
    int wgid = (xcd < 5) ? xcd * 120 + lin : 600 + (xcd - 5) * 119 + lin;
    int g, rem, w;
    if (wgid < 261)      { g = 0; rem = wgid;       w = 3; }
    else if (wgid < 522) { g = 1; rem = wgid - 261; w = 3; }
    else if (wgid < 783) { g = 2; rem = wgid - 522; w = 3; }
    else                 { g = 3; rem = wgid - 783; w = 2; }
    int it = rem / w, ntw = rem - it * w;
    m0 = it * 256; n0 = (g * 3 + ntw) * 256;
  } else {
    // 528 = 8 xcd * 66; groups of (batch, nt-pair), it-fastest
    int xcd = wg & 7, lin = wg >> 3;
    int wgid = xcd * 66 + lin;
    int gidx = wgid / 22, rem = wgid - gidx * 22;  // 24 groups of 22
    bb = gidx / 3; int pair = gidx - bb * 3;
    int it = rem >> 1, ntw = rem & 1;
    m0 = it * 256; n0 = (pair * 2 + ntw) * 256;
  }
  const short* Abase = Ag + (EPI == 0 ? (size_t)0 : (size_t)bb * MROW * PTOT);
  const short* Bbase = Bg + (EPI == 0 ? (size_t)0 : (size_t)bb * BTROWS * PTOT);

  int T = threadIdx.x, w = T >> 6, l = T & 63;
  int lr = l & 15, lg = l >> 4;
  int wm = w >> 2, wn = w & 3;

  // staging: 4 gld16/tile/thread; pre-swizzled global src, linear LDS dest
  const char* gsrc[4];
  int dst[4];
#pragma unroll
  for (int i = 0; i < 4; ++i) {
    int region = i >> 1, chunk = i & 1;
    int o = chunk * 8192 + w * 1024 + l * 16;
    int row = o >> 6;
    int colb = (o & 63) ^ (((o >> 7) & 3) << 4);
    const short* base = (region == 0) ? (Abase + (size_t)(m0 + row) * LDAe)
                                      : (Bbase + (size_t)(n0 + row) * LDBe);
    gsrc[i] = (const char*)base + colb;
    dst[i] = region * 16384 + o;
  }
  // swizzled read offsets
  int offA[8], offB[4];
#pragma unroll
  for (int m = 0; m < 8; ++m) {
    int x = (wm * 128 + m * 16 + lr) * 64 + lg * 16;
    offA[m] = x ^ (((x >> 7) & 3) << 4);
  }
#pragma unroll
  for (int n = 0; n < 4; ++n) {
    int x = (wn * 64 + n * 16 + lr) * 64 + lg * 16;
    offB[n] = 16384 + (x ^ (((x >> 7) & 3) << 4));
  }

  f32x4 acc[8][4];
  const f32x4 fz = {0.f, 0.f, 0.f, 0.f};
#pragma unroll
  for (int m = 0; m < 8; ++m)
#pragma unroll
    for (int n = 0; n < 4; ++n) acc[m][n] = fz;

  // prologue: stage K-tiles 0,1,2 into slots 0,1,2
#pragma unroll
  for (int pt = 0; pt < 3; ++pt)
#pragma unroll
    for (int i = 0; i < 4; ++i)
      gld16(gsrc[i] + (size_t)pt * 64, sm + (pt << 15) + dst[i]);
  VMW(8);                                  // tile 0 landed
  __builtin_amdgcn_s_barrier();

  int t = 0;
  for (; t < NT - 3; ++t) { TILE_BODY(t, 1, 8); }
  TILE_BODY(t, 0, 4); ++t;
  TILE_BODY(t, 0, 0); ++t;
  TILE_BODY(t, 0, -1);

  // epilogue
  if (EPI == 0) {
#pragma unroll
    for (int m = 0; m < 8; ++m) {
#pragma unroll
      for (int rg = 0; rg < 4; ++rg) {
        int gmi = m0 + wm * 128 + m * 16 + lg * 4 + rg;
        int i = gmi % PTOT;
        float* Mrow = Mout + (size_t)gmi * PTOT;
#pragma unroll
        for (int n = 0; n < 4; ++n) {
          int j = n0 + wn * 64 + n * 16 + lr;
          if (j < PM1) {
            int q2 = j + (j >= i);
            Mrow[q2] = acc[m][n][rg] + att_b[j];
          }
        }
      }
    }
  } else {
#pragma unroll
    for (int m = 0; m < 8; ++m) {
#pragma unroll
      for (int rg = 0; rg < 4; ++rg) {
        int i = m0 + wm * 128 + m * 16 + lg * 4 + rg;
        if (i < PTOT) {
          short* arow = attf + ((size_t)(bb * PTOT + i)) * DDIM;
#pragma unroll
          for (int n = 0; n < 4; ++n) {
            int d = n0 + wn * 64 + n * 16 + lr;
            if (d < DDIM) arow[d] = f2bf_rne(acc[m][n][rg]);
          }
        }
      }
    }
  }
}

// ---------------- kernel 5: row softmax in place on M + bf16 copy -------------
__global__ __launch_bounds__(256) void k_softmax(float* __restrict__ M,
                                                 short* __restrict__ Mbf) {
  __shared__ float red[8];
  int r = blockIdx.x;
  int b = r / PTOT, p = r - b * PTOT;
  float* pr = M + (size_t)r * PTOT;
  short* mb = Mbf + ((size_t)b * MROW + p) * PTOT;
  int t = threadIdx.x;
  bool has2 = (t < 348 - 256);              // 2784/8 = 348 chunks of 8
  float v0[8], v1[8];
  f32x4 a0 = *(const f32x4*)(pr + t * 8);
  f32x4 a1 = *(const f32x4*)(pr + t * 8 + 4);
  float mx = -3.0e38f;
#pragma unroll
  for (int e = 0; e < 4; ++e) {
    v0[e] = a0[e]; v0[4 + e] = a1[e];
    mx = fmaxf(mx, fmaxf(v0[e], v0[4 + e]));
  }
  if (has2) {
    f32x4 b0 = *(const f32x4*)(pr + (256 + t) * 8);
    f32x4 b1 = *(const f32x4*)(pr + (256 + t) * 8 + 4);
#pragma unroll
    for (int e = 0; e < 4; ++e) {
      v1[e] = b0[e]; v1[4 + e] = b1[e];
      mx = fmaxf(mx, fmaxf(v1[e], v1[4 + e]));
    }
  }
#pragma unroll
  for (int off = 32; off; off >>= 1) mx = fmaxf(mx, __shfl_xor(mx, off));
  if ((t & 63) == 0) red[t >> 6] = mx;
  __syncthreads();
  mx = fmaxf(fmaxf(red[0], red[1]), fmaxf(red[2], red[3]));
  float s = 0.f;
#pragma unroll
  for (int e = 0; e < 8; ++e) { v0[e] = __expf(v0[e] - mx); s += v0[e]; }
  if (has2) {
#pragma unroll
    for (int e = 0; e < 8; ++e) { v1[e] = __expf(v1[e] - mx); s += v1[e]; }
  }
#pragma unroll
  for (int off = 32; off; off >>= 1) s += __shfl_xor(s, off);
  if ((t & 63) == 0) red[4 + (t >> 6)] = s;
  __syncthreads();
  s = (red[4] + red[5]) + (red[6] + red[7]);
  float inv = 1.f / s;
  {
    f32x4 o0, o1; bf16x8 ob;
#pragma unroll
    for (int e = 0; e < 8; ++e) {
      float wv = v0[e] * inv;
      if (e < 4) o0[e] = wv; else o1[e - 4] = wv;
      ob[e] = f2bf_rne(wv);
    }
    *(f32x4*)(pr + t * 8) = o0;
    *(f32x4*)(pr + t * 8 + 4) = o1;
    *(bf16x8*)(mb + t * 8) = ob;
  }
  if (has2) {
    f32x4 o0, o1; bf16x8 ob;
#pragma unroll
    for (int e = 0; e < 8; ++e) {
      float wv = v1[e] * inv;
      if (e < 4) o0[e] = wv; else o1[e - 4] = wv;
      ob[e] = f2bf_rne(wv);
    }
    *(f32x4*)(pr + (256 + t) * 8) = o0;
    *(f32x4*)(pr + (256 + t) * 8 + 4) = o1;
    *(bf16x8*)(mb + (256 + t) * 8) = ob;
  }
}

// ---------------- kernel 7: heads GEMM + proposal assembly --------------------
__global__ __launch_bounds__(256) void k_head(
    const short* __restrict__ attf, const short* __restrict__ baf,
    const short* __restrict__ wbf, const float* __restrict__ bias80,
    const float* __restrict__ anch, float* __restrict__ out) {
  __shared__ short smA[64 * 32];
  __shared__ short smB[80 * 32];
  int r0 = blockIdx.x * 64;
  int t = threadIdx.x, wid = t >> 6, lane = t & 63;
  int rowa = t >> 2, kg = t & 3;
  const short* sA_att = attf + (size_t)(r0 + rowa) * DDIM + kg * 8;
  const short* sA_baf = baf + (size_t)(r0 + rowa) * DDIM + kg * 8;
  const short* sB0 = wbf + (size_t)rowa * KHEAD + kg * 8;
  const short* sB1 = wbf + (size_t)(64 + (t >> 2)) * KHEAD + (t & 3) * 8;
  char* lA = (char*)smA + wid * 1024;
  char* lB0 = (char*)smB + wid * 1024;
  char* lB1 = (char*)smB + 4096;
  int lr = lane & 15, lg = lane >> 4;
  const short* pA = smA + (wid * 16 + lr) * 32 + lg * 8;
  const short* pB = smB + lr * 32 + lg * 8;
  f32x4 acc[5];
  const f32x4 fz = {0.f, 0.f, 0.f, 0.f};
  for (int i2 = 0; i2 < 5; ++i2) acc[i2] = fz;
  for (int ks = 0; ks < 88; ++ks) {
    const short* sA = (ks < 44) ? (sA_att + ks * 32) : (sA_baf + (ks - 44) * 32);
    gld16(sA, lA);
    gld16(sB0 + ks * 32, lB0);
    if (t < 64) gld16(sB1 + ks * 32, lB1);
    __syncthreads();
    bf16x8 a = *(const bf16x8*)pA;
#pragma unroll
    for (int ni = 0; ni < 5; ++ni) {
      bf16x8 b = *(const bf16x8*)(pB + ni * 512);
      acc[ni] = __builtin_amdgcn_mfma_f32_16x16x32_bf16(a, b, acc[ni], 0, 0, 0);
    }
    __syncthreads();
  }
#pragma unroll
  for (int ni = 0; ni < 5; ++ni) {
#pragma unroll
    for (int rg = 0; rg < 4; ++rg) {
      int n = ni * 16 + lr;
      int i = wid * 16 + lg * 4 + rg;
      int rgl = r0 + i;
      int p = rgl % PTOT;
      float v = acc[ni][rg] + bias80[n];
      if (n < 2) {
        out[(size_t)rgl * 77 + n] = v;
      } else if (n == 2) {
        out[(size_t)rgl * 77 + 2] =
            (anch[(size_t)p * 77 + 2] + 1.f / (1.f + __expf(-v))) * 0.5f;
        out[(size_t)rgl * 77 + 3] = anch[(size_t)p * 77 + 3];
      } else if (n < 76) {
        out[(size_t)rgl * 77 + n + 1] = v + anch[(size_t)p * 77 + n + 1];
      }
    }
  }
}

extern "C" void kernel_launch(void* const* d_in, const int* in_sizes, int n_in,
                              void* d_out, int out_size, void* d_ws, size_t ws_size,
                              hipStream_t stream) {
  const float* x      = (const float*)d_in[0];
  const float* conv_w = (const float*)d_in[1];
  const float* conv_b = (const float*)d_in[2];
  const float* att_w  = (const float*)d_in[3];
  const float* att_b  = (const float*)d_in[4];
  const float* cls_w  = (const float*)d_in[5];
  const float* cls_b  = (const float*)d_in[6];
  const float* so_w   = (const float*)d_in[7];
  const float* so_b   = (const float*)d_in[8];
  const float* reg_w  = (const float*)d_in[9];
  const float* reg_b  = (const float*)d_in[10];
  const float* anchors= (const float*)d_in[11];
  const int*   cut_xs = (const int*)d_in[12];
  const unsigned char* invalid = (const unsigned char*)d_in[13];

  float* out_rp = (float*)d_out;
  float* Mmat = out_rp + (size_t)ROWS * 77;
  float* feat = Mmat + (size_t)ROWS * PTOT;

  // workspace layout, 319,742,720 B total (<= 320.9MB proven available).
  // attw aliases Mbf tail: written d2(prep), read d4(scores), overwritten
  // d5(softmax) -> safe, deterministic across replays.
  char* wsp = (char*)d_ws;
  short* baf    = (short*)wsp;                          // 62,717,952 (+256 pad)
  short* bafT   = (short*)(wsp + 62718208ULL);          // 8*1536*2784*2 = 68,419,584
  short* Mbf    = (short*)(wsp + 131137792ULL);         // 8*2816*2784*2 = 125,435,904
  short* attw   = (short*)(wsp + 248643840ULL);         // 2816*1408*2 = 7,929,856 (alias)
  short* wbf    = (short*)(wsp + 256573696ULL);         // 450,560
  float* bias80 = (float*)(wsp + 257024256ULL);         // 512
  short* attf   = (short*)(wsp + 257024768ULL);         // 62,717,952 -> 319,742,720

  k_conv<<<224, 256, 0, stream>>>(x, conv_w, conv_b, feat);
  k_prep<<<2048, 256, 0, stream>>>(att_w, cls_w, so_w, reg_w, cls_b, so_b, reg_b,
                                   attw, wbf, bias80, Mmat);
  k_gather<<<dim3(44, 24, 8), 256, 0, stream>>>(feat, cut_xs, invalid, baf, bafT);
  k_gemm256<0><<<957, 512, 0, stream>>>(baf, attw, att_b, Mmat, (short*)nullptr);
  k_softmax<<<ROWS, 256, 0, stream>>>(Mmat, Mbf);
  k_gemm256<1><<<528, 512, 0, stream>>>(Mbf, bafT, (const float*)nullptr,
                                        (float*)nullptr, attf);
  k_head<<<348, 256, 0, stream>>>(attf, baf, wbf, bias80, anchors, out_rp);
}